// Round 14
// baseline (567.255 us; speedup 1.0000x reference)
//
#include <hip/hip_runtime.h>
#include <math.h>

#define BB 32
#define LL 128
#define DM 64
#define DI 128
#define NV 50001
#define BL (BB*LL)       // 4096
#define TM 32
#define TN 512
#define NT2 98           // ceil(50001/512)
#define NPAD2 (NT2*TN)   // 50176

typedef float f32x4 __attribute__((ext_vector_type(4)));
typedef _Float16 h16x8 __attribute__((ext_vector_type(8)));

__device__ __forceinline__ float silu_f(float x) { return x / (1.0f + expf(-x)); }

// ================= fused pre-chain v2: 256 blocks = (b, token-eighth), 512 thr ==============
__global__ __launch_bounds__(512, 1) void k_pre(
    const int* __restrict__ ids, const float* __restrict__ item_emb,
    const float* __restrict__ pos_emb, const float* __restrict__ in_proj_w,
    const float* __restrict__ conv_w, const float* __restrict__ conv_b,
    const float* __restrict__ x_proj_w, const float* __restrict__ dt_proj_w,
    const float* __restrict__ dt_proj_b,
    float* __restrict__ zs_g, float* __restrict__ xcs_g,
    float* __restrict__ dbl_g, float* __restrict__ delta_g) {
    __shared__ float sq[19 * 68];     // embed rows (token T0-3+i), pitch 68
    __shared__ float px[19 * 132];    // x-half of in_proj, pitch 132
    __shared__ float cvS[16 * 132];   // conv+silu rows (token T0+j)
    __shared__ float dtS[16 * 4];     // dt ranks per token
    const int t = threadIdx.x;
    const int bb = blockIdx.x >> 3, e8 = blockIdx.x & 7;
    const int T0 = e8 * 16;

    // ---- phase 1: embedding ----
    {
        int d = t & 63;
        for (int i = t >> 6; i < 19; i += 8) {
            int tl = T0 - 3 + i;
            float v = 0.f;
            if (tl >= 0) {
                int id = ids[bb * LL + tl];
                if (id != 0) v = item_emb[id * DM + d] * 8.0f + pos_emb[tl * DM + d];
            }
            sq[i * 68 + d] = v;
        }
    }
    __syncthreads();
    // ---- phase 2: in_proj; thread owns col e, w-row in 16 f32x4 regs ----
    {
        int e = t & 255, half = t >> 8;
        f32x4 w4[16];
        const float* wr = in_proj_w + e * DM;
        #pragma unroll
        for (int k = 0; k < 16; k++) w4[k] = *(const f32x4*)&wr[4 * k];
        int i0 = half ? 10 : 0, i1 = half ? 19 : 10;
        for (int i = i0; i < i1; i++) {
            float a = 0.f;
            #pragma unroll
            for (int k = 0; k < 16; k++) {
                f32x4 s = *(const f32x4*)&sq[i * 68 + 4 * k];   // wave-uniform row: broadcast
                a += s.x * w4[k].x + s.y * w4[k].y + s.z * w4[k].z + s.w * w4[k].w;
            }
            if (e < 128) px[i * 132 + e] = a;
            else if (i >= 3) zs_g[(size_t)(bb * LL + T0 + i - 3) * DI + (e - 128)] = silu_f(a);
        }
    }
    __syncthreads();
    // ---- phase 3: causal conv + silu ----
    {
        int c = t & 127;
        float cw0 = conv_w[c * 4], cw1 = conv_w[c * 4 + 1];
        float cw2 = conv_w[c * 4 + 2], cw3 = conv_w[c * 4 + 3];
        float cb = conv_b[c];
        #pragma unroll
        for (int m = 0; m < 4; m++) {
            int j = 4 * m + (t >> 7);
            float v = silu_f(cb + px[j * 132 + c] * cw0 + px[(j + 1) * 132 + c] * cw1
                                + px[(j + 2) * 132 + c] * cw2 + px[(j + 3) * 132 + c] * cw3);
            cvS[j * 132 + c] = v;
            xcs_g[(size_t)(bb * LL + T0 + j) * DI + c] = v;
        }
    }
    __syncthreads();
    // ---- phase 4: x_proj; main covers e=4..67 (B|C), w-row in 32 f32x4 regs ----
    {
        int e = 4 + (t & 63), jg = t >> 6;
        f32x4 w4[32];
        const float* wr = x_proj_w + (size_t)e * DI;
        #pragma unroll
        for (int k = 0; k < 32; k++) w4[k] = *(const f32x4*)&wr[4 * k];
        #pragma unroll
        for (int jj = 0; jj < 2; jj++) {
            int j = jg + 8 * jj;
            float a = 0.f;
            #pragma unroll
            for (int k = 0; k < 32; k++) {
                f32x4 x = *(const f32x4*)&cvS[j * 132 + 4 * k];
                a += x.x * w4[k].x + x.y * w4[k].y + x.z * w4[k].z + x.w * w4[k].w;
            }
            dbl_g[(size_t)(bb * LL + T0 + j) * 64 + (e - 4)] = a;
        }
        if (t < 64) {
            int j2 = t >> 2, e2 = t & 3;
            const float* wr2 = x_proj_w + (size_t)e2 * DI;
            float a = 0.f;
            #pragma unroll
            for (int k = 0; k < 32; k++) {
                f32x4 x = *(const f32x4*)&cvS[j2 * 132 + 4 * k];
                f32x4 w2 = *(const f32x4*)&wr2[4 * k];
                a += x.x * w2.x + x.y * w2.y + x.z * w2.z + x.w * w2.w;
            }
            dtS[j2 * 4 + e2] = a;
        }
    }
    __syncthreads();
    // ---- phase 5: delta = softplus(dt @ dt_proj^T + b) ----
    {
        int c = t & 127;
        float dw0 = dt_proj_w[c * 4], dw1 = dt_proj_w[c * 4 + 1];
        float dw2 = dt_proj_w[c * 4 + 2], dw3 = dt_proj_w[c * 4 + 3];
        float db = dt_proj_b[c];
        #pragma unroll
        for (int m = 0; m < 4; m++) {
            int j = 4 * m + (t >> 7);
            float a = db + dtS[j * 4] * dw0 + dtS[j * 4 + 1] * dw1
                         + dtS[j * 4 + 2] * dw2 + dtS[j * 4 + 3] * dw3;
            float sp = (a > 20.f) ? a : log1pf(expf(a));
            delta_g[(size_t)(bb * LL + T0 + j) * DI + c] = sp;
        }
    }
}

// ================= scan: grid 256 = (b, channel-eighth), 512 thr ======
__global__ __launch_bounds__(512, 1) void k_scan(
    const float* __restrict__ delta_g, const float* __restrict__ xcs_g,
    const float* __restrict__ dbl_g, const float* __restrict__ zs_g,
    const float* __restrict__ A_log, const float* __restrict__ Dp,
    float* __restrict__ y_g) {
    const int t = threadIdx.x;
    const int b = blockIdx.x >> 3, ce = blockIdx.x & 7;
    const int grp = t >> 5, s = t & 31;
    const int c = ce * 16 + grp;
    const size_t r0 = (size_t)(b * LL);
    float Acs = -expf(A_log[c * 32 + s]);
    float Dc = Dp[c];
    float h = 0.f;
    float Bt = dbl_g[r0 * 64 + s], Ct = dbl_g[r0 * 64 + 32 + s];
    float dlt = delta_g[r0 * DI + c], xct = xcs_g[r0 * DI + c];
    float zt = zs_g[r0 * DI + c];
    for (int tt = 0; tt < LL; tt++) {
        float Bn = 0.f, Cn = 0.f, zn = 0.f, dn = 0.f, xn = 0.f;
        if (tt < LL - 1) {
            size_t rn = r0 + tt + 1;
            Bn = dbl_g[rn * 64 + s]; Cn = dbl_g[rn * 64 + 32 + s];
            dn = delta_g[rn * DI + c]; xn = xcs_g[rn * DI + c];
            zn = zs_g[rn * DI + c];
        }
        h = expf(dlt * Acs) * h + (dlt * Bt) * xct;
        float p = h * Ct;
        #pragma unroll
        for (int off = 16; off; off >>= 1) p += __shfl_xor(p, off, 32);
        if (s == 0) y_g[(r0 + tt) * DI + c] = (p + Dc * xct) * zt;
        dlt = dn; xct = xn; Bt = Bn; Ct = Cn; zt = zn;
    }
}

// ================= emb -> fp16 (* 2^10) ==========
__global__ void k_cvt_emb(const float* __restrict__ emb, _Float16* __restrict__ embh) {
    int i = blockIdx.x * 256 + threadIdx.x;
    int r = i >> 6, d = i & 63;
    float v = (r < NV) ? emb[(size_t)r * 64 + d] * 1024.0f : 0.f;
    embh[i] = (_Float16)v;
}

// ================= logits (R11 structure + FUSED out_proj A-tile) =======================
// Phase A computes outp rows m0..m0+31 from y,w (identical math/order to R13 k_outproj —
// bit-identical values) into As; ~free under the store wall. Then R11-exact GEMM+store.
__global__ __launch_bounds__(256, 2) void k_logits(
    const float* __restrict__ y, const float* __restrict__ wo,
    const _Float16* __restrict__ Bm, float* __restrict__ logits) {
    __shared__ _Float16 As[TM * 72];      // 4.6 KB
    __shared__ _Float16 Bs[TN * 72];      // 73.7 KB; front reused for y-tile, later fp32 C tile
    const int m0 = blockIdx.x * TM;       // m fastest
    const int n0 = blockIdx.y * TN;
    const int t = threadIdx.x;

    // ---- phase 0: stage y tile (32 x 128 f32) into front of Bs ----
    float* ys = (float*)Bs;               // pitch 132 (16.9 KB)
    #pragma unroll
    for (int q = 0; q < 4; q++) {
        int idx = t + q * 256;            // f32x4 chunk, 1024 total
        int r = idx >> 5, c4 = idx & 31;
        *(f32x4*)&ys[r * 132 + 4 * c4] = *(const f32x4*)&y[(size_t)(m0 + r) * DI + 4 * c4];
    }
    __syncthreads();
    // ---- phase A: out_proj -> As fp16*2^18. thread: col d=t&63, rows (t>>6)+4*jj ----
    {
        int d = t & 63, rq = t >> 6;
        f32x4 w4[32];
        const float* wr = wo + (size_t)d * DI;
        #pragma unroll
        for (int k = 0; k < 32; k++) w4[k] = *(const f32x4*)&wr[4 * k];
        #pragma unroll
        for (int jj = 0; jj < 8; jj++) {
            int r = rq + 4 * jj;          // wave-uniform -> ys reads broadcast
            float a = 0.f;
            #pragma unroll
            for (int k = 0; k < 32; k++) {
                f32x4 x = *(const f32x4*)&ys[r * 132 + 4 * k];
                a += x.x * w4[k].x + x.y * w4[k].y + x.z * w4[k].z + x.w * w4[k].w;
            }
            As[r * 72 + d] = (_Float16)(a * 262144.0f);   // * 2^18
        }
    }
    __syncthreads();
    // ---- stage B: 512 rows x 128 B -> 16 chunks per thread (overwrites ys) ----
    #pragma unroll
    for (int q = 0; q < 16; q++) {
        int idx = t + q * 256;
        int r = idx >> 3, c8 = idx & 7;
        *(h16x8*)&Bs[r * 72 + c8 * 8] = *(const h16x8*)&Bm[(size_t)(n0 + r) * 64 + c8 * 8];
    }
    __syncthreads();

    const int lane = t & 63, wv = t >> 6;
    const int lr = lane & 15, lg = lane >> 4;
    f32x4 acc[2][8];
    #pragma unroll
    for (int mi = 0; mi < 2; mi++)
        #pragma unroll
        for (int ni = 0; ni < 8; ni++)
            acc[mi][ni] = f32x4{0.f, 0.f, 0.f, 0.f};

    #pragma unroll
    for (int step = 0; step < 2; step++) {
        int kb = step * 32 + lg * 8;
        h16x8 a[2], b[8];
        #pragma unroll
        for (int mi = 0; mi < 2; mi++)
            a[mi] = *(const h16x8*)&As[(16 * mi + lr) * 72 + kb];
        #pragma unroll
        for (int ni = 0; ni < 8; ni++)
            b[ni] = *(const h16x8*)&Bs[(128 * wv + 16 * ni + lr) * 72 + kb];
        #pragma unroll
        for (int mi = 0; mi < 2; mi++)
            #pragma unroll
            for (int ni = 0; ni < 8; ni++)
                acc[mi][ni] = __builtin_amdgcn_mfma_f32_16x16x32_f16(a[mi], b[ni], acc[mi][ni], 0, 0, 0);
    }
    __syncthreads();

    float* Cs = (float*)Bs;
    const float SC = 3.7252902984619140625e-09f;   // 2^-28
    #pragma unroll
    for (int mi = 0; mi < 2; mi++)
        #pragma unroll
        for (int ni = 0; ni < 8; ni++) {
            int col = 128 * wv + 16 * ni + lr;
            #pragma unroll
            for (int j = 0; j < 4; j++) {
                int row = 16 * mi + 4 * lg + j;
                Cs[row * 517 + col] = acc[mi][ni][j] * SC;
            }
        }
    __syncthreads();

    #pragma unroll
    for (int q = 0; q < 16; q++) {
        int r = 2 * q + (t >> 7);
        int c = t & 127;
        int grow = m0 + r;
        int s = (4 - (grow & 3)) & 3;
        float* dst = logits + (size_t)grow * NV + n0;
        const float* src = Cs + r * 517;
        if (s == 0) {
            int col = 4 * c;
            int gc = n0 + col;
            if (gc + 3 < NV) {
                __builtin_nontemporal_store(*(const f32x4*)&src[col], (f32x4*)&dst[col]);
            } else {
                #pragma unroll
                for (int e = 0; e < 4; e++)
                    if (gc + e < NV) __builtin_nontemporal_store(src[col + e], &dst[col + e]);
            }
        } else {
            if (c == 0) {
                for (int e = 0; e < s; e++)
                    if (n0 + e < NV) __builtin_nontemporal_store(src[e], &dst[e]);
            }
            if (c < 127) {
                int col = s + 4 * c;
                int gc = n0 + col;
                if (gc + 3 < NV) {
                    __builtin_nontemporal_store(*(const f32x4*)&src[col], (f32x4*)&dst[col]);
                } else {
                    #pragma unroll
                    for (int e = 0; e < 4; e++)
                        if (gc + e < NV) __builtin_nontemporal_store(src[col + e], &dst[col + e]);
                }
            } else {
                for (int e = s + 508; e < 512; e++)
                    if (n0 + e < NV) __builtin_nontemporal_store(src[e], &dst[e]);
            }
        }
    }
}

extern "C" void kernel_launch(void* const* d_in, const int* in_sizes, int n_in,
                              void* d_out, int out_size, void* d_ws, size_t ws_size,
                              hipStream_t stream) {
    const int*   ids       = (const int*)  d_in[0];
    const float* item_emb  = (const float*)d_in[1];
    const float* pos_emb   = (const float*)d_in[2];
    const float* in_proj_w = (const float*)d_in[3];
    const float* conv_w    = (const float*)d_in[4];
    const float* conv_b    = (const float*)d_in[5];
    const float* x_proj_w  = (const float*)d_in[6];
    const float* dt_proj_w = (const float*)d_in[7];
    const float* dt_proj_b = (const float*)d_in[8];
    const float* A_log     = (const float*)d_in[9];
    const float* Dp        = (const float*)d_in[10];
    const float* out_proj_w= (const float*)d_in[11];
    float* logits = (float*)d_out;

    float* ws     = (float*)d_ws;
    float* zs     = ws;                      // BL*128  (silu(z))
    float* xcs    = zs + (size_t)BL * DI;    // BL*128
    float* dblg   = xcs + (size_t)BL * DI;   // BL*64   (B|C)
    float* deltag = dblg + (size_t)BL * 64;  // BL*128
    float* yg     = deltag + (size_t)BL * DI;                 // BL*128
    _Float16* embh  = (_Float16*)(yg + (size_t)BL * DI);      // NPAD2*64 halves

    k_cvt_emb<<<(NPAD2 * 64) / 256, 256, 0, stream>>>(item_emb, embh);
    k_pre<<<256, 512, 0, stream>>>(ids, item_emb, pos_emb, in_proj_w, conv_w, conv_b,
                                   x_proj_w, dt_proj_w, dt_proj_b,
                                   zs, xcs, dblg, deltag);
    k_scan<<<256, 512, 0, stream>>>(deltag, xcs, dblg, zs, A_log, Dp, yg);
    dim3 lgd(BL / TM, NT2);   // x = 128 m-tiles (fastest), y = 98 n-tiles
    k_logits<<<lgd, 256, 0, stream>>>(yg, out_proj_w, embh, logits);
}

// Round 15
// 460.253 us; speedup vs baseline: 1.2325x; 1.2325x over previous
//
#include <hip/hip_runtime.h>
#include <math.h>

#define BB 32
#define LL 128
#define DM 64
#define DI 128
#define NV 50001
#define BL (BB*LL)       // 4096
#define TM 32
#define TN 512
#define NT2 98           // ceil(50001/512)

typedef float f32x4 __attribute__((ext_vector_type(4)));
typedef _Float16 h16x8 __attribute__((ext_vector_type(8)));

__device__ __forceinline__ float silu_f(float x) { return x / (1.0f + expf(-x)); }

// ================= fused pre-chain v2: 256 blocks = (b, token-eighth), 512 thr ==============
__global__ __launch_bounds__(512, 1) void k_pre(
    const int* __restrict__ ids, const float* __restrict__ item_emb,
    const float* __restrict__ pos_emb, const float* __restrict__ in_proj_w,
    const float* __restrict__ conv_w, const float* __restrict__ conv_b,
    const float* __restrict__ x_proj_w, const float* __restrict__ dt_proj_w,
    const float* __restrict__ dt_proj_b,
    float* __restrict__ zs_g, float* __restrict__ xcs_g,
    float* __restrict__ dbl_g, float* __restrict__ delta_g) {
    __shared__ float sq[19 * 68];     // embed rows (token T0-3+i), pitch 68
    __shared__ float px[19 * 132];    // x-half of in_proj, pitch 132
    __shared__ float cvS[16 * 132];   // conv+silu rows (token T0+j)
    __shared__ float dtS[16 * 4];     // dt ranks per token
    const int t = threadIdx.x;
    const int bb = blockIdx.x >> 3, e8 = blockIdx.x & 7;
    const int T0 = e8 * 16;

    // ---- phase 1: embedding ----
    {
        int d = t & 63;
        for (int i = t >> 6; i < 19; i += 8) {
            int tl = T0 - 3 + i;
            float v = 0.f;
            if (tl >= 0) {
                int id = ids[bb * LL + tl];
                if (id != 0) v = item_emb[id * DM + d] * 8.0f + pos_emb[tl * DM + d];
            }
            sq[i * 68 + d] = v;
        }
    }
    __syncthreads();
    // ---- phase 2: in_proj; thread owns col e, w-row in 16 f32x4 regs ----
    {
        int e = t & 255, half = t >> 8;
        f32x4 w4[16];
        const float* wr = in_proj_w + e * DM;
        #pragma unroll
        for (int k = 0; k < 16; k++) w4[k] = *(const f32x4*)&wr[4 * k];
        int i0 = half ? 10 : 0, i1 = half ? 19 : 10;
        for (int i = i0; i < i1; i++) {
            float a = 0.f;
            #pragma unroll
            for (int k = 0; k < 16; k++) {
                f32x4 s = *(const f32x4*)&sq[i * 68 + 4 * k];   // wave-uniform row: broadcast
                a += s.x * w4[k].x + s.y * w4[k].y + s.z * w4[k].z + s.w * w4[k].w;
            }
            if (e < 128) px[i * 132 + e] = a;
            else if (i >= 3) zs_g[(size_t)(bb * LL + T0 + i - 3) * DI + (e - 128)] = silu_f(a);
        }
    }
    __syncthreads();
    // ---- phase 3: causal conv + silu ----
    {
        int c = t & 127;
        float cw0 = conv_w[c * 4], cw1 = conv_w[c * 4 + 1];
        float cw2 = conv_w[c * 4 + 2], cw3 = conv_w[c * 4 + 3];
        float cb = conv_b[c];
        #pragma unroll
        for (int m = 0; m < 4; m++) {
            int j = 4 * m + (t >> 7);
            float v = silu_f(cb + px[j * 132 + c] * cw0 + px[(j + 1) * 132 + c] * cw1
                                + px[(j + 2) * 132 + c] * cw2 + px[(j + 3) * 132 + c] * cw3);
            cvS[j * 132 + c] = v;
            xcs_g[(size_t)(bb * LL + T0 + j) * DI + c] = v;
        }
    }
    __syncthreads();
    // ---- phase 4: x_proj; main covers e=4..67 (B|C), w-row in 32 f32x4 regs ----
    {
        int e = 4 + (t & 63), jg = t >> 6;
        f32x4 w4[32];
        const float* wr = x_proj_w + (size_t)e * DI;
        #pragma unroll
        for (int k = 0; k < 32; k++) w4[k] = *(const f32x4*)&wr[4 * k];
        #pragma unroll
        for (int jj = 0; jj < 2; jj++) {
            int j = jg + 8 * jj;
            float a = 0.f;
            #pragma unroll
            for (int k = 0; k < 32; k++) {
                f32x4 x = *(const f32x4*)&cvS[j * 132 + 4 * k];
                a += x.x * w4[k].x + x.y * w4[k].y + x.z * w4[k].z + x.w * w4[k].w;
            }
            dbl_g[(size_t)(bb * LL + T0 + j) * 64 + (e - 4)] = a;
        }
        if (t < 64) {
            int j2 = t >> 2, e2 = t & 3;
            const float* wr2 = x_proj_w + (size_t)e2 * DI;
            float a = 0.f;
            #pragma unroll
            for (int k = 0; k < 32; k++) {
                f32x4 x = *(const f32x4*)&cvS[j2 * 132 + 4 * k];
                f32x4 w2 = *(const f32x4*)&wr2[4 * k];
                a += x.x * w2.x + x.y * w2.y + x.z * w2.z + x.w * w2.w;
            }
            dtS[j2 * 4 + e2] = a;
        }
    }
    __syncthreads();
    // ---- phase 5: delta = softplus(dt @ dt_proj^T + b) ----
    {
        int c = t & 127;
        float dw0 = dt_proj_w[c * 4], dw1 = dt_proj_w[c * 4 + 1];
        float dw2 = dt_proj_w[c * 4 + 2], dw3 = dt_proj_w[c * 4 + 3];
        float db = dt_proj_b[c];
        #pragma unroll
        for (int m = 0; m < 4; m++) {
            int j = 4 * m + (t >> 7);
            float a = db + dtS[j * 4] * dw0 + dtS[j * 4 + 1] * dw1
                         + dtS[j * 4 + 2] * dw2 + dtS[j * 4 + 3] * dw3;
            float sp = (a > 20.f) ? a : log1pf(expf(a));
            delta_g[(size_t)(bb * LL + T0 + j) * DI + c] = sp;
        }
    }
}

// ================= scan: grid 256 = (b, channel-eighth), 512 thr ======
__global__ __launch_bounds__(512, 1) void k_scan(
    const float* __restrict__ delta_g, const float* __restrict__ xcs_g,
    const float* __restrict__ dbl_g, const float* __restrict__ zs_g,
    const float* __restrict__ A_log, const float* __restrict__ Dp,
    float* __restrict__ y_g) {
    const int t = threadIdx.x;
    const int b = blockIdx.x >> 3, ce = blockIdx.x & 7;
    const int grp = t >> 5, s = t & 31;
    const int c = ce * 16 + grp;
    const size_t r0 = (size_t)(b * LL);
    float Acs = -expf(A_log[c * 32 + s]);
    float Dc = Dp[c];
    float h = 0.f;
    float Bt = dbl_g[r0 * 64 + s], Ct = dbl_g[r0 * 64 + 32 + s];
    float dlt = delta_g[r0 * DI + c], xct = xcs_g[r0 * DI + c];
    float zt = zs_g[r0 * DI + c];
    for (int tt = 0; tt < LL; tt++) {
        float Bn = 0.f, Cn = 0.f, zn = 0.f, dn = 0.f, xn = 0.f;
        if (tt < LL - 1) {
            size_t rn = r0 + tt + 1;
            Bn = dbl_g[rn * 64 + s]; Cn = dbl_g[rn * 64 + 32 + s];
            dn = delta_g[rn * DI + c]; xn = xcs_g[rn * DI + c];
            zn = zs_g[rn * DI + c];
        }
        h = expf(dlt * Acs) * h + (dlt * Bt) * xct;
        float p = h * Ct;
        #pragma unroll
        for (int off = 16; off; off >>= 1) p += __shfl_xor(p, off, 32);
        if (s == 0) y_g[(r0 + tt) * DI + c] = (p + Dc * xct) * zt;
        dlt = dn; xct = xn; Bt = Bn; Ct = Cn; zt = zn;
    }
}

// ================= out_proj: 512 blocks x 256 thr, 8 rows/block, w in regs ==========
__global__ __launch_bounds__(256, 2) void k_outproj(
    const float* __restrict__ y, const float* __restrict__ w,
    _Float16* __restrict__ outp_h) {
    __shared__ float ys[8 * 132];
    const int t = threadIdx.x;
    const int r0 = blockIdx.x * 8;
    {
        int r = t >> 5, c4 = t & 31;
        *(f32x4*)&ys[r * 132 + 4 * c4] = *(const f32x4*)&y[(size_t)(r0 + r) * DI + 4 * c4];
    }
    __syncthreads();
    int d = t & 63, rh = t >> 6;
    f32x4 w4[32];
    const float* wr = w + d * DI;
    #pragma unroll
    for (int k = 0; k < 32; k++) w4[k] = *(const f32x4*)&wr[4 * k];
    #pragma unroll
    for (int jj = 0; jj < 2; jj++) {
        int r = rh + 4 * jj;
        float a = 0.f;
        #pragma unroll
        for (int k = 0; k < 32; k++) {
            f32x4 x = *(const f32x4*)&ys[r * 132 + 4 * k];
            a += x.x * w4[k].x + x.y * w4[k].y + x.z * w4[k].z + x.w * w4[k].w;
        }
        outp_h[(size_t)(r0 + r) * 64 + d] = (_Float16)(a * 262144.0f);   // * 2^18
    }
}

// ================= logits (R11/R13 structure; B staged from fp32 emb, inline cvt) =========
__global__ __launch_bounds__(256, 2) void k_logits(
    const _Float16* __restrict__ A, const float* __restrict__ embf,
    float* __restrict__ logits) {
    __shared__ _Float16 As[TM * 72];      // 4.6 KB
    __shared__ _Float16 Bs[TN * 72];      // 73.7 KB, reused as fp32 C tile
    const int m0 = blockIdx.x * TM;       // m fastest
    const int n0 = blockIdx.y * TN;
    const int t = threadIdx.x;

    {
        int r = t >> 3, c8 = t & 7;
        *(h16x8*)&As[r * 72 + c8 * 8] = *(const h16x8*)&A[(size_t)(m0 + r) * 64 + c8 * 8];
    }
    // stage B: 512 rows x 64 f32 -> convert to fp16*2^10 inline (matches old k_cvt_emb math)
    #pragma unroll
    for (int q = 0; q < 16; q++) {
        int idx = t + q * 256;
        int r = idx >> 3, c8 = idx & 7;
        int vr = n0 + r;
        h16x8 hv = {0, 0, 0, 0, 0, 0, 0, 0};
        if (vr < NV) {
            f32x4 v0 = *(const f32x4*)&embf[(size_t)vr * 64 + c8 * 8];
            f32x4 v1 = *(const f32x4*)&embf[(size_t)vr * 64 + c8 * 8 + 4];
            #pragma unroll
            for (int e = 0; e < 4; e++) {
                hv[e]     = (_Float16)(v0[e] * 1024.0f);
                hv[e + 4] = (_Float16)(v1[e] * 1024.0f);
            }
        }
        *(h16x8*)&Bs[r * 72 + c8 * 8] = hv;
    }
    __syncthreads();

    const int lane = t & 63, wv = t >> 6;
    const int lr = lane & 15, lg = lane >> 4;
    f32x4 acc[2][8];
    #pragma unroll
    for (int mi = 0; mi < 2; mi++)
        #pragma unroll
        for (int ni = 0; ni < 8; ni++)
            acc[mi][ni] = f32x4{0.f, 0.f, 0.f, 0.f};

    #pragma unroll
    for (int step = 0; step < 2; step++) {
        int kb = step * 32 + lg * 8;
        h16x8 a[2], b[8];
        #pragma unroll
        for (int mi = 0; mi < 2; mi++)
            a[mi] = *(const h16x8*)&As[(16 * mi + lr) * 72 + kb];
        #pragma unroll
        for (int ni = 0; ni < 8; ni++)
            b[ni] = *(const h16x8*)&Bs[(128 * wv + 16 * ni + lr) * 72 + kb];
        #pragma unroll
        for (int mi = 0; mi < 2; mi++)
            #pragma unroll
            for (int ni = 0; ni < 8; ni++)
                acc[mi][ni] = __builtin_amdgcn_mfma_f32_16x16x32_f16(a[mi], b[ni], acc[mi][ni], 0, 0, 0);
    }
    __syncthreads();

    float* Cs = (float*)Bs;
    const float SC = 3.7252902984619140625e-09f;   // 2^-28
    #pragma unroll
    for (int mi = 0; mi < 2; mi++)
        #pragma unroll
        for (int ni = 0; ni < 8; ni++) {
            int col = 128 * wv + 16 * ni + lr;
            #pragma unroll
            for (int j = 0; j < 4; j++) {
                int row = 16 * mi + 4 * lg + j;
                Cs[row * 517 + col] = acc[mi][ni][j] * SC;
            }
        }
    __syncthreads();

    #pragma unroll
    for (int q = 0; q < 16; q++) {
        int r = 2 * q + (t >> 7);
        int c = t & 127;
        int grow = m0 + r;
        int s = (4 - (grow & 3)) & 3;
        float* dst = logits + (size_t)grow * NV + n0;
        const float* src = Cs + r * 517;
        if (s == 0) {
            int col = 4 * c;
            int gc = n0 + col;
            if (gc + 3 < NV) {
                __builtin_nontemporal_store(*(const f32x4*)&src[col], (f32x4*)&dst[col]);
            } else {
                #pragma unroll
                for (int e = 0; e < 4; e++)
                    if (gc + e < NV) __builtin_nontemporal_store(src[col + e], &dst[col + e]);
            }
        } else {
            if (c == 0) {
                for (int e = 0; e < s; e++)
                    if (n0 + e < NV) __builtin_nontemporal_store(src[e], &dst[e]);
            }
            if (c < 127) {
                int col = s + 4 * c;
                int gc = n0 + col;
                if (gc + 3 < NV) {
                    __builtin_nontemporal_store(*(const f32x4*)&src[col], (f32x4*)&dst[col]);
                } else {
                    #pragma unroll
                    for (int e = 0; e < 4; e++)
                        if (gc + e < NV) __builtin_nontemporal_store(src[col + e], &dst[col + e]);
                }
            } else {
                for (int e = s + 508; e < 512; e++)
                    if (n0 + e < NV) __builtin_nontemporal_store(src[e], &dst[e]);
            }
        }
    }
}

extern "C" void kernel_launch(void* const* d_in, const int* in_sizes, int n_in,
                              void* d_out, int out_size, void* d_ws, size_t ws_size,
                              hipStream_t stream) {
    const int*   ids       = (const int*)  d_in[0];
    const float* item_emb  = (const float*)d_in[1];
    const float* pos_emb   = (const float*)d_in[2];
    const float* in_proj_w = (const float*)d_in[3];
    const float* conv_w    = (const float*)d_in[4];
    const float* conv_b    = (const float*)d_in[5];
    const float* x_proj_w  = (const float*)d_in[6];
    const float* dt_proj_w = (const float*)d_in[7];
    const float* dt_proj_b = (const float*)d_in[8];
    const float* A_log     = (const float*)d_in[9];
    const float* Dp        = (const float*)d_in[10];
    const float* out_proj_w= (const float*)d_in[11];
    float* logits = (float*)d_out;

    float* ws     = (float*)d_ws;
    float* zs     = ws;                      // BL*128  (silu(z))
    float* xcs    = zs + (size_t)BL * DI;    // BL*128
    float* dblg   = xcs + (size_t)BL * DI;   // BL*64   (B|C)
    float* deltag = dblg + (size_t)BL * 64;  // BL*128
    float* yg     = deltag + (size_t)BL * DI;                 // BL*128
    _Float16* outph = (_Float16*)(yg + (size_t)BL * DI);      // BL*64 halves

    k_pre<<<256, 512, 0, stream>>>(ids, item_emb, pos_emb, in_proj_w, conv_w, conv_b,
                                   x_proj_w, dt_proj_w, dt_proj_b,
                                   zs, xcs, dblg, deltag);
    k_scan<<<256, 512, 0, stream>>>(deltag, xcs, dblg, zs, A_log, Dp, yg);
    k_outproj<<<BL / 8, 256, 0, stream>>>(yg, out_proj_w, outph);
    dim3 lgd(BL / TM, NT2);   // x = 128 m-tiles (fastest), y = 98 n-tiles
    k_logits<<<lgd, 256, 0, stream>>>(outph, item_emb, logits);
}

// Round 16
// 364.624 us; speedup vs baseline: 1.5557x; 1.2623x over previous
//
#include <hip/hip_runtime.h>
#include <math.h>

#define BB 32
#define LL 128
#define DM 64
#define DI 128
#define NV 50001
#define BL (BB*LL)       // 4096
#define TM 32
#define TN 512
#define NT2 98           // ceil(50001/512)
#define NPAD2 (NT2*TN)   // 50176

typedef float f32x4 __attribute__((ext_vector_type(4)));
typedef _Float16 h16x8 __attribute__((ext_vector_type(8)));

__device__ __forceinline__ float silu_f(float x) { return x / (1.0f + expf(-x)); }

// ================= fused pre-chain v2: 256 blocks = (b, token-eighth), 512 thr ==============
__global__ __launch_bounds__(512, 1) void k_pre(
    const int* __restrict__ ids, const float* __restrict__ item_emb,
    const float* __restrict__ pos_emb, const float* __restrict__ in_proj_w,
    const float* __restrict__ conv_w, const float* __restrict__ conv_b,
    const float* __restrict__ x_proj_w, const float* __restrict__ dt_proj_w,
    const float* __restrict__ dt_proj_b,
    float* __restrict__ zs_g, float* __restrict__ xcs_g,
    float* __restrict__ dbl_g, float* __restrict__ delta_g) {
    __shared__ float sq[19 * 68];     // embed rows (token T0-3+i), pitch 68
    __shared__ float px[19 * 132];    // x-half of in_proj, pitch 132
    __shared__ float cvS[16 * 132];   // conv+silu rows (token T0+j)
    __shared__ float dtS[16 * 4];     // dt ranks per token
    const int t = threadIdx.x;
    const int bb = blockIdx.x >> 3, e8 = blockIdx.x & 7;
    const int T0 = e8 * 16;

    // ---- phase 1: embedding ----
    {
        int d = t & 63;
        for (int i = t >> 6; i < 19; i += 8) {
            int tl = T0 - 3 + i;
            float v = 0.f;
            if (tl >= 0) {
                int id = ids[bb * LL + tl];
                if (id != 0) v = item_emb[id * DM + d] * 8.0f + pos_emb[tl * DM + d];
            }
            sq[i * 68 + d] = v;
        }
    }
    __syncthreads();
    // ---- phase 2: in_proj; thread owns col e, w-row in 16 f32x4 regs ----
    {
        int e = t & 255, half = t >> 8;
        f32x4 w4[16];
        const float* wr = in_proj_w + e * DM;
        #pragma unroll
        for (int k = 0; k < 16; k++) w4[k] = *(const f32x4*)&wr[4 * k];
        int i0 = half ? 10 : 0, i1 = half ? 19 : 10;
        for (int i = i0; i < i1; i++) {
            float a = 0.f;
            #pragma unroll
            for (int k = 0; k < 16; k++) {
                f32x4 s = *(const f32x4*)&sq[i * 68 + 4 * k];   // wave-uniform row: broadcast
                a += s.x * w4[k].x + s.y * w4[k].y + s.z * w4[k].z + s.w * w4[k].w;
            }
            if (e < 128) px[i * 132 + e] = a;
            else if (i >= 3) zs_g[(size_t)(bb * LL + T0 + i - 3) * DI + (e - 128)] = silu_f(a);
        }
    }
    __syncthreads();
    // ---- phase 3: causal conv + silu ----
    {
        int c = t & 127;
        float cw0 = conv_w[c * 4], cw1 = conv_w[c * 4 + 1];
        float cw2 = conv_w[c * 4 + 2], cw3 = conv_w[c * 4 + 3];
        float cb = conv_b[c];
        #pragma unroll
        for (int m = 0; m < 4; m++) {
            int j = 4 * m + (t >> 7);
            float v = silu_f(cb + px[j * 132 + c] * cw0 + px[(j + 1) * 132 + c] * cw1
                                + px[(j + 2) * 132 + c] * cw2 + px[(j + 3) * 132 + c] * cw3);
            cvS[j * 132 + c] = v;
            xcs_g[(size_t)(bb * LL + T0 + j) * DI + c] = v;
        }
    }
    __syncthreads();
    // ---- phase 4: x_proj; main covers e=4..67 (B|C), w-row in 32 f32x4 regs ----
    {
        int e = 4 + (t & 63), jg = t >> 6;
        f32x4 w4[32];
        const float* wr = x_proj_w + (size_t)e * DI;
        #pragma unroll
        for (int k = 0; k < 32; k++) w4[k] = *(const f32x4*)&wr[4 * k];
        #pragma unroll
        for (int jj = 0; jj < 2; jj++) {
            int j = jg + 8 * jj;
            float a = 0.f;
            #pragma unroll
            for (int k = 0; k < 32; k++) {
                f32x4 x = *(const f32x4*)&cvS[j * 132 + 4 * k];
                a += x.x * w4[k].x + x.y * w4[k].y + x.z * w4[k].z + x.w * w4[k].w;
            }
            dbl_g[(size_t)(bb * LL + T0 + j) * 64 + (e - 4)] = a;
        }
        if (t < 64) {
            int j2 = t >> 2, e2 = t & 3;
            const float* wr2 = x_proj_w + (size_t)e2 * DI;
            float a = 0.f;
            #pragma unroll
            for (int k = 0; k < 32; k++) {
                f32x4 x = *(const f32x4*)&cvS[j2 * 132 + 4 * k];
                f32x4 w2 = *(const f32x4*)&wr2[4 * k];
                a += x.x * w2.x + x.y * w2.y + x.z * w2.z + x.w * w2.w;
            }
            dtS[j2 * 4 + e2] = a;
        }
    }
    __syncthreads();
    // ---- phase 5: delta = softplus(dt @ dt_proj^T + b) ----
    {
        int c = t & 127;
        float dw0 = dt_proj_w[c * 4], dw1 = dt_proj_w[c * 4 + 1];
        float dw2 = dt_proj_w[c * 4 + 2], dw3 = dt_proj_w[c * 4 + 3];
        float db = dt_proj_b[c];
        #pragma unroll
        for (int m = 0; m < 4; m++) {
            int j = 4 * m + (t >> 7);
            float a = db + dtS[j * 4] * dw0 + dtS[j * 4 + 1] * dw1
                         + dtS[j * 4 + 2] * dw2 + dtS[j * 4 + 3] * dw3;
            float sp = (a > 20.f) ? a : log1pf(expf(a));
            delta_g[(size_t)(bb * LL + T0 + j) * DI + c] = sp;
        }
    }
}

// ================= scan: grid 256 = (b, channel-eighth), 512 thr ======
__global__ __launch_bounds__(512, 1) void k_scan(
    const float* __restrict__ delta_g, const float* __restrict__ xcs_g,
    const float* __restrict__ dbl_g, const float* __restrict__ zs_g,
    const float* __restrict__ A_log, const float* __restrict__ Dp,
    float* __restrict__ y_g) {
    const int t = threadIdx.x;
    const int b = blockIdx.x >> 3, ce = blockIdx.x & 7;
    const int grp = t >> 5, s = t & 31;
    const int c = ce * 16 + grp;
    const size_t r0 = (size_t)(b * LL);
    float Acs = -expf(A_log[c * 32 + s]);
    float Dc = Dp[c];
    float h = 0.f;
    float Bt = dbl_g[r0 * 64 + s], Ct = dbl_g[r0 * 64 + 32 + s];
    float dlt = delta_g[r0 * DI + c], xct = xcs_g[r0 * DI + c];
    float zt = zs_g[r0 * DI + c];
    for (int tt = 0; tt < LL; tt++) {
        float Bn = 0.f, Cn = 0.f, zn = 0.f, dn = 0.f, xn = 0.f;
        if (tt < LL - 1) {
            size_t rn = r0 + tt + 1;
            Bn = dbl_g[rn * 64 + s]; Cn = dbl_g[rn * 64 + 32 + s];
            dn = delta_g[rn * DI + c]; xn = xcs_g[rn * DI + c];
            zn = zs_g[rn * DI + c];
        }
        h = expf(dlt * Acs) * h + (dlt * Bt) * xct;
        float p = h * Ct;
        #pragma unroll
        for (int off = 16; off; off >>= 1) p += __shfl_xor(p, off, 32);
        if (s == 0) y_g[(r0 + tt) * DI + c] = (p + Dc * xct) * zt;
        dlt = dn; xct = xn; Bt = Bn; Ct = Cn; zt = zn;
    }
}

// ================= out_proj v2: 512 blocks x 256 thr, 8 rows/block, w in regs ==========
__global__ __launch_bounds__(256, 2) void k_outproj(
    const float* __restrict__ y, const float* __restrict__ w,
    _Float16* __restrict__ outp_h) {
    __shared__ float ys[8 * 132];
    const int t = threadIdx.x;
    const int r0 = blockIdx.x * 8;
    {
        int r = t >> 5, c4 = t & 31;
        *(f32x4*)&ys[r * 132 + 4 * c4] = *(const f32x4*)&y[(size_t)(r0 + r) * DI + 4 * c4];
    }
    __syncthreads();
    int d = t & 63, rh = t >> 6;
    f32x4 w4[32];
    const float* wr = w + d * DI;
    #pragma unroll
    for (int k = 0; k < 32; k++) w4[k] = *(const f32x4*)&wr[4 * k];
    #pragma unroll
    for (int jj = 0; jj < 2; jj++) {
        int r = rh + 4 * jj;
        float a = 0.f;
        #pragma unroll
        for (int k = 0; k < 32; k++) {
            f32x4 x = *(const f32x4*)&ys[r * 132 + 4 * k];
            a += x.x * w4[k].x + x.y * w4[k].y + x.z * w4[k].z + x.w * w4[k].w;
        }
        outp_h[(size_t)(r0 + r) * 64 + d] = (_Float16)(a * 262144.0f);   // * 2^18
    }
}

// ================= emb -> fp16 (* 2^10) ==========
__global__ void k_cvt_emb(const float* __restrict__ emb, _Float16* __restrict__ embh) {
    int i = blockIdx.x * 256 + threadIdx.x;
    int r = i >> 6, d = i & 63;
    float v = (r < NV) ? emb[(size_t)r * 64 + d] * 1024.0f : 0.f;
    embh[i] = (_Float16)v;
}

// ================= logits (R11 exact — measured best): 32x512 tiles, nt stores ==========
__global__ __launch_bounds__(256, 2) void k_logits(
    const _Float16* __restrict__ A, const _Float16* __restrict__ Bm,
    float* __restrict__ logits) {
    __shared__ _Float16 As[TM * 72];      // 4.6 KB
    __shared__ _Float16 Bs[TN * 72];      // 73.7 KB, reused as fp32 C tile
    const int m0 = blockIdx.x * TM;       // m fastest
    const int n0 = blockIdx.y * TN;
    const int t = threadIdx.x;

    {
        int r = t >> 3, c8 = t & 7;
        *(h16x8*)&As[r * 72 + c8 * 8] = *(const h16x8*)&A[(size_t)(m0 + r) * 64 + c8 * 8];
    }
    #pragma unroll
    for (int q = 0; q < 16; q++) {
        int idx = t + q * 256;
        int r = idx >> 3, c8 = idx & 7;
        *(h16x8*)&Bs[r * 72 + c8 * 8] = *(const h16x8*)&Bm[(size_t)(n0 + r) * 64 + c8 * 8];
    }
    __syncthreads();

    const int lane = t & 63, wv = t >> 6;
    const int lr = lane & 15, lg = lane >> 4;
    f32x4 acc[2][8];
    #pragma unroll
    for (int mi = 0; mi < 2; mi++)
        #pragma unroll
        for (int ni = 0; ni < 8; ni++)
            acc[mi][ni] = f32x4{0.f, 0.f, 0.f, 0.f};

    #pragma unroll
    for (int step = 0; step < 2; step++) {
        int kb = step * 32 + lg * 8;
        h16x8 a[2], b[8];
        #pragma unroll
        for (int mi = 0; mi < 2; mi++)
            a[mi] = *(const h16x8*)&As[(16 * mi + lr) * 72 + kb];
        #pragma unroll
        for (int ni = 0; ni < 8; ni++)
            b[ni] = *(const h16x8*)&Bs[(128 * wv + 16 * ni + lr) * 72 + kb];
        #pragma unroll
        for (int mi = 0; mi < 2; mi++)
            #pragma unroll
            for (int ni = 0; ni < 8; ni++)
                acc[mi][ni] = __builtin_amdgcn_mfma_f32_16x16x32_f16(a[mi], b[ni], acc[mi][ni], 0, 0, 0);
    }
    __syncthreads();

    float* Cs = (float*)Bs;
    const float SC = 3.7252902984619140625e-09f;   // 2^-28
    #pragma unroll
    for (int mi = 0; mi < 2; mi++)
        #pragma unroll
        for (int ni = 0; ni < 8; ni++) {
            int col = 128 * wv + 16 * ni + lr;
            #pragma unroll
            for (int j = 0; j < 4; j++) {
                int row = 16 * mi + 4 * lg + j;
                Cs[row * 517 + col] = acc[mi][ni][j] * SC;
            }
        }
    __syncthreads();

    #pragma unroll
    for (int q = 0; q < 16; q++) {
        int r = 2 * q + (t >> 7);
        int c = t & 127;
        int grow = m0 + r;
        int s = (4 - (grow & 3)) & 3;
        float* dst = logits + (size_t)grow * NV + n0;
        const float* src = Cs + r * 517;
        if (s == 0) {
            int col = 4 * c;
            int gc = n0 + col;
            if (gc + 3 < NV) {
                __builtin_nontemporal_store(*(const f32x4*)&src[col], (f32x4*)&dst[col]);
            } else {
                #pragma unroll
                for (int e = 0; e < 4; e++)
                    if (gc + e < NV) __builtin_nontemporal_store(src[col + e], &dst[col + e]);
            }
        } else {
            if (c == 0) {
                for (int e = 0; e < s; e++)
                    if (n0 + e < NV) __builtin_nontemporal_store(src[e], &dst[e]);
            }
            if (c < 127) {
                int col = s + 4 * c;
                int gc = n0 + col;
                if (gc + 3 < NV) {
                    __builtin_nontemporal_store(*(const f32x4*)&src[col], (f32x4*)&dst[col]);
                } else {
                    #pragma unroll
                    for (int e = 0; e < 4; e++)
                        if (gc + e < NV) __builtin_nontemporal_store(src[col + e], &dst[col + e]);
                }
            } else {
                for (int e = s + 508; e < 512; e++)
                    if (n0 + e < NV) __builtin_nontemporal_store(src[e], &dst[e]);
            }
        }
    }
}

extern "C" void kernel_launch(void* const* d_in, const int* in_sizes, int n_in,
                              void* d_out, int out_size, void* d_ws, size_t ws_size,
                              hipStream_t stream) {
    const int*   ids       = (const int*)  d_in[0];
    const float* item_emb  = (const float*)d_in[1];
    const float* pos_emb   = (const float*)d_in[2];
    const float* in_proj_w = (const float*)d_in[3];
    const float* conv_w    = (const float*)d_in[4];
    const float* conv_b    = (const float*)d_in[5];
    const float* x_proj_w  = (const float*)d_in[6];
    const float* dt_proj_w = (const float*)d_in[7];
    const float* dt_proj_b = (const float*)d_in[8];
    const float* A_log     = (const float*)d_in[9];
    const float* Dp        = (const float*)d_in[10];
    const float* out_proj_w= (const float*)d_in[11];
    float* logits = (float*)d_out;

    float* ws     = (float*)d_ws;
    float* zs     = ws;                      // BL*128  (silu(z))
    float* xcs    = zs + (size_t)BL * DI;    // BL*128
    float* dblg   = xcs + (size_t)BL * DI;   // BL*64   (B|C)
    float* deltag = dblg + (size_t)BL * 64;  // BL*128
    float* yg     = deltag + (size_t)BL * DI;                 // BL*128
    _Float16* outph = (_Float16*)(yg + (size_t)BL * DI);      // BL*64 halves
    _Float16* embh  = outph + (size_t)BL * 64;                // NPAD2*64 halves

    k_cvt_emb<<<(NPAD2 * 64) / 256, 256, 0, stream>>>(item_emb, embh);
    k_pre<<<256, 512, 0, stream>>>(ids, item_emb, pos_emb, in_proj_w, conv_w, conv_b,
                                   x_proj_w, dt_proj_w, dt_proj_b,
                                   zs, xcs, dblg, deltag);
    k_scan<<<256, 512, 0, stream>>>(deltag, xcs, dblg, zs, A_log, Dp, yg);
    k_outproj<<<BL / 8, 256, 0, stream>>>(yg, out_proj_w, outph);
    dim3 lgd(BL / TM, NT2);   // x = 128 m-tiles (fastest), y = 98 n-tiles
    k_logits<<<lgd, 256, 0, stream>>>(outph, embh, logits);
}